// Round 3
// baseline (12.350 us; speedup 1.0000x reference)
//
#include <hip/hip_runtime.h>
#include <hip/hip_bf16.h>

// Problem constants (from reference): B=8, N=4096, D=256, K=2048.
// Output = merged[:, :K] = ru = gather(r, idx_unbiased) — everything else in
// the reference is dead code (concat puts ru first, slice takes exactly K rows).
//
// Pure gather: out[b,i,:] = r[b, idx_unbiased[b,i], :].
// Mapping: one float4 per thread, exact-fit grid. Each 64-lane wave covers
// exactly one 256-float row (64 float4), so idx[row] is wave-uniform and the
// row read is 16 consecutive 64B lines (fully coalesced).
// Output is write-once -> non-temporal stores (skip L2 pollution, keep r hot).
// Note: __builtin_nontemporal_store needs a clang vector type, not HIP float4.

namespace {
typedef float f32x4 __attribute__((ext_vector_type(4)));

constexpr int B = 8;
constexpr int N = 4096;
constexpr int K = 2048;
constexpr int V = 64;                     // float4 per row (D=256)
constexpr int TOTAL = B * K * V;          // 1,048,576 float4
}

__global__ void __launch_bounds__(256) gather_ru_kernel(
    const f32x4* __restrict__ r,       // (B, N, D) as f32x4
    const int* __restrict__ idx,       // (B, K)
    f32x4* __restrict__ out)           // (B, K, D) as f32x4
{
    const int t    = blockIdx.x * 256 + threadIdx.x;
    const int dvec = t & (V - 1);          // lane within the row
    const int row  = t >> 6;               // b*K + i  (wave-uniform)
    const int b    = row >> 11;            // row / K
    const int src  = idx[row];             // wave-uniform broadcast load
    const f32x4 v = r[((long)b * N + src) * V + dvec];
    __builtin_nontemporal_store(v, &out[t]);
}

extern "C" void kernel_launch(void* const* d_in, const int* in_sizes, int n_in,
                              void* d_out, int out_size, void* d_ws, size_t ws_size,
                              hipStream_t stream) {
    // setup_inputs order: r(0), e(1), idx_unbiased(2), idx_biased(3),
    //                     Wc1_w(4), Wc1_b(5), Wc2_w(6), Wc2_b(7)
    const f32x4* r   = (const f32x4*)d_in[0];
    const int* idx_u = (const int*)d_in[2];
    f32x4* out       = (f32x4*)d_out;

    gather_ru_kernel<<<TOTAL / 256, 256, 0, stream>>>(r, idx_u, out);
}

// Round 4
// 11.116 us; speedup vs baseline: 1.1110x; 1.1110x over previous
//
#include <hip/hip_runtime.h>
#include <hip/hip_bf16.h>

// Problem constants (from reference): B=8, N=4096, D=256, K=2048.
// Output = merged[:, :K] = ru = gather(r, idx_unbiased) — everything else in
// the reference is dead code (concat puts ru first, slice takes exactly K rows).
//
// Pure gather: out[b,i,:] = r[b, idx_unbiased[b,i], :].
// R4: plain stores (NT store regressed in R3), ILP=4 — each thread owns 4
// rows spaced B*K/4 apart, so the 4 idx loads issue together and the 4
// dependent row-gathers issue together (4 outstanding HBM chains per lane).

namespace {
constexpr int B = 8;
constexpr int N = 4096;
constexpr int K = 2048;
constexpr int V = 64;                      // float4 per row (D=256)
constexpr int ROWS = B * K;                // 16384
constexpr int ILP = 4;
constexpr int THREADS = ROWS / ILP * V;    // 262,144
constexpr int ROW_STRIDE = ROWS / ILP;     // 4096 rows between chains
}

__global__ void __launch_bounds__(256) gather_ru_kernel(
    const float4* __restrict__ r,      // (B, N, D) as float4
    const int* __restrict__ idx,       // (B, K)
    float4* __restrict__ out)          // (B, K, D) as float4
{
    const int t    = blockIdx.x * 256 + threadIdx.x;
    const int dvec = t & (V - 1);          // lane within the row
    const int row0 = t >> 6;               // first of 4 rows (wave-uniform)

    int rows[ILP], srcs[ILP];
#pragma unroll
    for (int j = 0; j < ILP; ++j) {
        rows[j] = row0 + j * ROW_STRIDE;
        srcs[j] = idx[rows[j]];            // 4 independent index loads
    }
    float4 v[ILP];
#pragma unroll
    for (int j = 0; j < ILP; ++j) {
        const int b = rows[j] >> 11;       // row / K
        v[j] = r[((long)b * N + srcs[j]) * V + dvec];  // 4 independent gathers
    }
#pragma unroll
    for (int j = 0; j < ILP; ++j) {
        out[(long)rows[j] * V + dvec] = v[j];
    }
}

extern "C" void kernel_launch(void* const* d_in, const int* in_sizes, int n_in,
                              void* d_out, int out_size, void* d_ws, size_t ws_size,
                              hipStream_t stream) {
    // setup_inputs order: r(0), e(1), idx_unbiased(2), idx_biased(3),
    //                     Wc1_w(4), Wc1_b(5), Wc2_w(6), Wc2_b(7)
    const float4* r  = (const float4*)d_in[0];
    const int* idx_u = (const int*)d_in[2];
    float4* out      = (float4*)d_out;

    gather_ru_kernel<<<THREADS / 256, 256, 0, stream>>>(r, idx_u, out);
}